// Round 13
// baseline (461.043 us; speedup 1.0000x reference)
//
#include <hip/hip_runtime.h>
#include <hip/hip_bf16.h>
#include <hip/hip_fp16.h>
#include <math.h>

#define N_NODES 50000
#define N_EDGES 800000
#define E_TOT   (N_EDGES + N_NODES)
#define F_IN    64
#define HIDDEN  128
#define HEADS   4
#define OUT_DIM 256
#define N_GRAPHS 1024
#define BN_EPS  1e-5f
#define SLOPE   0.2f

#define SCAN_TILE 2048
#define N_TILES   ((N_NODES + SCAN_TILE - 1) / SCAN_TILE)   // 25
#define POOL_NODES 128

// ---------------- CSR build ----------------

// 4 edges/thread: 4 independent atomic chains in flight (latency-bound kernel)
__global__ void hist_kernel(const int* __restrict__ ei, int* __restrict__ deg) {
    int base = blockIdx.x * blockDim.x * 4 + threadIdx.x;
    #pragma unroll
    for (int u = 0; u < 4; ++u) {
        int i = base + u * 256;
        if (i < E_TOT) {
            int d = (i < N_EDGES) ? ei[N_EDGES + i] : (i - N_EDGES);
            atomicAdd(&deg[d], 1);
        }
    }
}

__global__ void scan_partial_kernel(const int* __restrict__ deg, int* __restrict__ tile_sums) {
    __shared__ int wsum[4];
    int tile = blockIdx.x;
    int tid = threadIdx.x;
    int base = tile * SCAN_TILE + tid * 8;
    int s = 0;
    #pragma unroll
    for (int k = 0; k < 8; ++k) {
        int i = base + k;
        if (i < N_NODES) s += deg[i];
    }
    int lane = tid & 63;
    for (int off = 1; off < 64; off <<= 1) s += __shfl_xor(s, off, 64);
    if (lane == 0) wsum[tid >> 6] = s;
    __syncthreads();
    if (tid == 0) tile_sums[tile] = wsum[0] + wsum[1] + wsum[2] + wsum[3];
}

__global__ void scan_tilesums_kernel(const int* __restrict__ tile_sums, int* __restrict__ tile_off) {
    if (threadIdx.x == 0) {
        int acc = 0;
        for (int t = 0; t < N_TILES; ++t) { tile_off[t] = acc; acc += tile_sums[t]; }
    }
}

__global__ void scan_apply_kernel(const int* __restrict__ deg, const int* __restrict__ tile_off,
                                  int* __restrict__ row_start) {
    __shared__ int wsum[4];
    int tile = blockIdx.x;
    int tid = threadIdx.x;
    int lane = tid & 63;
    int wid = tid >> 6;
    int base = tile * SCAN_TILE + tid * 8;
    int v[8];
    int tsum = 0;
    #pragma unroll
    for (int k = 0; k < 8; ++k) {
        int i = base + k;
        v[k] = (i < N_NODES) ? deg[i] : 0;
        tsum += v[k];
    }
    int sc = tsum;
    for (int off = 1; off < 64; off <<= 1) {
        int t = __shfl_up(sc, off, 64);
        if (lane >= off) sc += t;
    }
    if (lane == 63) wsum[wid] = sc;
    __syncthreads();
    int woff = 0;
    for (int w = 0; w < 4; ++w) woff += (w < wid) ? wsum[w] : 0;
    __syncthreads();
    int toff = tile_off[tile] + woff + (sc - tsum);
    #pragma unroll
    for (int k = 0; k < 8; ++k) {
        int i = base + k;
        if (i < N_NODES) row_start[i] = toff;
        toff += v[k];
    }
    if (tile == 0 && tid == 0) row_start[N_NODES] = E_TOT;
}

// 4 edges/thread: batch loads, then 4 independent atomic+store chains
__global__ void scatter_kernel(const int* __restrict__ ei, const int* __restrict__ row_start,
                               int* __restrict__ cursor, int* __restrict__ csr_src) {
    int base = blockIdx.x * blockDim.x * 4 + threadIdx.x;
    int s[4], d[4];
    bool ok[4];
    #pragma unroll
    for (int u = 0; u < 4; ++u) {
        int i = base + u * 256;
        ok[u] = i < E_TOT;
        if (ok[u]) {
            if (i < N_EDGES) { s[u] = ei[i]; d[u] = ei[N_EDGES + i]; }
            else             { s[u] = i - N_EDGES; d[u] = s[u]; }
        }
    }
    int pos[4];
    #pragma unroll
    for (int u = 0; u < 4; ++u)
        if (ok[u]) pos[u] = atomicAdd(&cursor[d[u]], 1);
    #pragma unroll
    for (int u = 0; u < 4; ++u)
        if (ok[u]) csr_src[row_start[d[u]] + pos[u]] = s[u];
}

// ---------------- LDS-staged GEMM + attention scores (H stored fp16) ----------------
template<int FIN>
__global__ __launch_bounds__(256) void gemm_att_kernel(
        const float* __restrict__ X, const float* __restrict__ W,
        const float* __restrict__ a_src, const float* __restrict__ a_dst,
        __half* __restrict__ H, float* __restrict__ es, float* __restrict__ ed) {
    __shared__ float Wl[FIN * HIDDEN];
    int tid = threadIdx.x;
    for (int i = tid * 4; i < FIN * HIDDEN; i += 256 * 4) {
        *reinterpret_cast<float4*>(&Wl[i]) = *reinterpret_cast<const float4*>(&W[i]);
    }
    __syncthreads();

    int cg = tid & 15;
    int np = tid >> 4;
    int nb = blockIdx.x * 64 + np * 4;
    int j0 = cg * 8;

    bool ok[4];
    const float* xp[4];
    #pragma unroll
    for (int t = 0; t < 4; ++t) {
        ok[t] = (nb + t) < N_NODES;
        xp[t] = X + (size_t)(ok[t] ? nb + t : 0) * FIN;
    }
    float acc[4][8];
    #pragma unroll
    for (int t = 0; t < 4; ++t)
        #pragma unroll
        for (int c = 0; c < 8; ++c) acc[t][c] = 0.f;

    for (int k = 0; k < FIN; k += 4) {
        float4 xa[4];
        #pragma unroll
        for (int t = 0; t < 4; ++t) xa[t] = *reinterpret_cast<const float4*>(xp[t] + k);
        #pragma unroll
        for (int kk = 0; kk < 4; ++kk) {
            const float4 wA = *reinterpret_cast<const float4*>(&Wl[(k + kk) * HIDDEN + j0]);
            const float4 wB = *reinterpret_cast<const float4*>(&Wl[(k + kk) * HIDDEN + j0 + 4]);
            #pragma unroll
            for (int t = 0; t < 4; ++t) {
                float xv = (kk == 0) ? xa[t].x : (kk == 1) ? xa[t].y : (kk == 2) ? xa[t].z : xa[t].w;
                acc[t][0] += xv * wA.x; acc[t][1] += xv * wA.y;
                acc[t][2] += xv * wA.z; acc[t][3] += xv * wA.w;
                acc[t][4] += xv * wB.x; acc[t][5] += xv * wB.y;
                acc[t][6] += xv * wB.z; acc[t][7] += xv * wB.w;
            }
        }
    }

    #pragma unroll
    for (int t = 0; t < 4; ++t) {
        int n = nb + t;
        if (ok[t]) {
            union { __half2 h2[4]; float4 f4; } pk;
            pk.h2[0] = __floats2half2_rn(acc[t][0], acc[t][1]);
            pk.h2[1] = __floats2half2_rn(acc[t][2], acc[t][3]);
            pk.h2[2] = __floats2half2_rn(acc[t][4], acc[t][5]);
            pk.h2[3] = __floats2half2_rn(acc[t][6], acc[t][7]);
            *reinterpret_cast<float4*>(H + (size_t)n * HIDDEN + j0) = pk.f4;
        }
        float vs = 0.f, vd = 0.f;
        #pragma unroll
        for (int c = 0; c < 8; ++c) {
            vs += acc[t][c] * a_src[j0 + c];
            vd += acc[t][c] * a_dst[j0 + c];
        }
        vs += __shfl_xor(vs, 1, 64); vs += __shfl_xor(vs, 2, 64);
        vd += __shfl_xor(vd, 1, 64); vd += __shfl_xor(vd, 2, 64);
        if ((cg & 3) == 0 && ok[t]) {
            int h = cg >> 2;
            es[n * HEADS + h] = vs;
            ed[n * HEADS + h] = vd;
        }
    }
}

// ---------------- per-node GAT aggregation (1 wave / node, fp16 gather, 4x unroll) ----------------
__global__ void gat_aggregate_kernel(const __half* __restrict__ H, const float* __restrict__ es,
                                     const float* __restrict__ ed, const int* __restrict__ row_start,
                                     const int* __restrict__ csr_src, const float* __restrict__ bias,
                                     float* __restrict__ out) {
    int lane = threadIdx.x & 63;
    int n = blockIdx.x * 4 + (threadIdx.x >> 6);
    if (n >= N_NODES) return;
    int hid = lane >> 4;
    float edn = ed[n * HEADS + hid];
    int k0 = row_start[n], k1 = row_start[n + 1];
    const __half2* Hp = reinterpret_cast<const __half2*>(H);
    float dsum = 0.f, accx = 0.f, accy = 0.f;
    int k = k0;
    for (; k + 3 < k1; k += 4) {
        int s0 = csr_src[k];
        int s1 = csr_src[k + 1];
        int s2 = csr_src[k + 2];
        int s3 = csr_src[k + 3];
        float e0 = es[s0 * HEADS + hid];
        float e1 = es[s1 * HEADS + hid];
        float e2 = es[s2 * HEADS + hid];
        float e3 = es[s3 * HEADS + hid];
        __half2 h0 = Hp[(size_t)s0 * (HIDDEN / 2) + lane];
        __half2 h1 = Hp[(size_t)s1 * (HIDDEN / 2) + lane];
        __half2 h2 = Hp[(size_t)s2 * (HIDDEN / 2) + lane];
        __half2 h3 = Hp[(size_t)s3 * (HIDDEN / 2) + lane];
        e0 += edn; e1 += edn; e2 += edn; e3 += edn;
        e0 = (e0 > 0.f) ? e0 : (SLOPE * e0);
        e1 = (e1 > 0.f) ? e1 : (SLOPE * e1);
        e2 = (e2 > 0.f) ? e2 : (SLOPE * e2);
        e3 = (e3 > 0.f) ? e3 : (SLOPE * e3);
        float ex0 = __expf(e0);
        float ex1 = __expf(e1);
        float ex2 = __expf(e2);
        float ex3 = __expf(e3);
        float2 f0 = __half22float2(h0);
        float2 f1 = __half22float2(h1);
        float2 f2 = __half22float2(h2);
        float2 f3 = __half22float2(h3);
        dsum += (ex0 + ex1) + (ex2 + ex3);
        accx += ex0 * f0.x + ex1 * f1.x + ex2 * f2.x + ex3 * f3.x;
        accy += ex0 * f0.y + ex1 * f1.y + ex2 * f2.y + ex3 * f3.y;
    }
    for (; k < k1; ++k) {
        int s0 = csr_src[k];
        float e0 = es[s0 * HEADS + hid] + edn;
        __half2 h0 = Hp[(size_t)s0 * (HIDDEN / 2) + lane];
        e0 = (e0 > 0.f) ? e0 : (SLOPE * e0);
        float ex0 = __expf(e0);
        float2 f0 = __half22float2(h0);
        dsum += ex0;
        accx += ex0 * f0.x;
        accy += ex0 * f0.y;
    }
    float inv = 1.f / (dsum + 1e-16f);
    int j = 2 * lane;
    out[(size_t)n * HIDDEN + j]     = accx * inv + bias[j];
    out[(size_t)n * HIDDEN + j + 1] = accy * inv + bias[j + 1];
}

// ---------------- BatchNorm (2-pass) + ELU ----------------
__global__ void bn_stats_kernel(const float* __restrict__ X, float* __restrict__ stats) {
    int c = threadIdx.x & 127;
    int r0 = blockIdx.x * 2 + (threadIdx.x >> 7);
    float s = 0.f, s2 = 0.f;
    for (int n = r0; n < N_NODES; n += gridDim.x * 2) {
        float v = X[(size_t)n * HIDDEN + c];
        s += v;
        s2 += v * v;
    }
    atomicAdd(&stats[c], s);
    atomicAdd(&stats[HIDDEN + c], s2);
}

__global__ void bn_apply_kernel(float* __restrict__ X, const float* __restrict__ stats,
                                const float* __restrict__ g, const float* __restrict__ b) {
    const float invN = 1.f / (float)N_NODES;
    int i = blockIdx.x * blockDim.x + threadIdx.x;
    const int total = N_NODES * HIDDEN;
    for (; i < total; i += gridDim.x * blockDim.x) {
        int c = i & 127;
        float mu = stats[c] * invN;
        float var = stats[HIDDEN + c] * invN - mu * mu;
        float v = (X[i] - mu) * rsqrtf(var + BN_EPS) * g[c] + b[c];
        X[i] = (v > 0.f) ? v : expm1f(v);
    }
}

// layer-2: BN+ELU fused into pooling, exploiting SORTED batch
__global__ __launch_bounds__(256) void bn_apply_pool_kernel(
        const float* __restrict__ X, const float* __restrict__ stats,
        const float* __restrict__ g, const float* __restrict__ b,
        const int* __restrict__ batch,
        float* __restrict__ psum, float* __restrict__ pcnt) {
    const float invN = 1.f / (float)N_NODES;
    int c = threadIdx.x & 127;
    int h = threadIdx.x >> 7;
    int n0 = blockIdx.x * POOL_NODES + h * (POOL_NODES / 2);
    int n1 = n0 + POOL_NODES / 2;
    if (n1 > N_NODES) n1 = N_NODES;
    if (n0 >= n1) return;
    float mu = stats[c] * invN;
    float var = stats[HIDDEN + c] * invN - mu * mu;
    float sc = rsqrtf(var + BN_EPS) * g[c];
    float sh = b[c] - mu * sc;
    int cur = batch[n0];
    float racc = 0.f, rcnt = 0.f;
    for (int n = n0; n < n1; ++n) {
        int gi = batch[n];
        if (gi != cur) {
            atomicAdd(&psum[cur * HIDDEN + c], racc);
            if (c == 0) atomicAdd(&pcnt[cur], rcnt);
            racc = 0.f; rcnt = 0.f; cur = gi;
        }
        float v = X[(size_t)n * HIDDEN + c] * sc + sh;
        v = (v > 0.f) ? v : expm1f(v);
        racc += v;
        rcnt += 1.f;
    }
    atomicAdd(&psum[cur * HIDDEN + c], racc);
    if (c == 0) atomicAdd(&pcnt[cur], rcnt);
}

// ---------------- final linear ----------------
__global__ void final_kernel(const float* __restrict__ psum, const float* __restrict__ pcnt,
                             const float* __restrict__ Wlin, const float* __restrict__ blin,
                             float* __restrict__ out) {
    int idx = blockIdx.x * blockDim.x + threadIdx.x;
    int g = idx >> 8, o = idx & 255;
    float invc = 1.f / fmaxf(pcnt[g], 1.f);
    float acc = blin[o];
    const float* pr = psum + g * HIDDEN;
    for (int j = 0; j < HIDDEN; ++j)
        acc += pr[j] * invc * Wlin[j * OUT_DIM + o];
    out[idx] = acc;
}

// ---------------- launch ----------------

extern "C" void kernel_launch(void* const* d_in, const int* in_sizes, int n_in,
                              void* d_out, int out_size, void* d_ws, size_t ws_size,
                              hipStream_t stream) {
    const float* x    = (const float*)d_in[0];
    const int*   ei   = (const int*)d_in[1];
    const int*   batch= (const int*)d_in[2];
    const float* W1   = (const float*)d_in[3];
    const float* as1  = (const float*)d_in[4];
    const float* ad1  = (const float*)d_in[5];
    const float* b1   = (const float*)d_in[6];
    const float* W2   = (const float*)d_in[7];
    const float* as2  = (const float*)d_in[8];
    const float* ad2  = (const float*)d_in[9];
    const float* b2   = (const float*)d_in[10];
    const float* bn1g = (const float*)d_in[11];
    const float* bn1b = (const float*)d_in[12];
    const float* bn2g = (const float*)d_in[13];
    const float* bn2b = (const float*)d_in[14];
    const float* Wlin = (const float*)d_in[15];
    const float* blin = (const float*)d_in[16];
    float* out = (float*)d_out;

    char* ws = (char*)d_ws;
    const size_t SZ_H = (size_t)N_NODES * HIDDEN * 4;
    __half* A       = (__half*)(ws);                      // fp16 H
    float* B        = (float*)(ws + SZ_H);
    size_t off = 2 * SZ_H;
    float* es       = (float*)(ws + off); off += (size_t)N_NODES * HEADS * 4;
    float* ed       = (float*)(ws + off); off += (size_t)N_NODES * HEADS * 4;
    int*   row_start= (int*)(ws + off);   off += ((size_t)(N_NODES + 1) * 4 + 511) & ~511ull;
    int*   csr_src  = (int*)(ws + off);   off += ((size_t)E_TOT * 4 + 511) & ~511ull;
    int*   tile_sums= (int*)(ws + off);   off += ((size_t)N_TILES * 4 + 511) & ~511ull;
    int*   tile_off = (int*)(ws + off);   off += ((size_t)N_TILES * 4 + 511) & ~511ull;
    size_t zoff = off;
    int*   deg      = (int*)(ws + off);   off += (size_t)N_NODES * 4;
    int*   cursor   = (int*)(ws + off);   off += (size_t)N_NODES * 4;
    float* stats1   = (float*)(ws + off); off += 2 * HIDDEN * 4;
    float* stats2   = (float*)(ws + off); off += 2 * HIDDEN * 4;
    float* psum     = (float*)(ws + off); off += (size_t)N_GRAPHS * HIDDEN * 4;
    float* pcnt     = (float*)(ws + off); off += (size_t)N_GRAPHS * 4;
    size_t zbytes = off - zoff;
    (void)ws_size; (void)n_in; (void)in_sizes; (void)out_size;

    hipMemsetAsync(ws + zoff, 0, zbytes, stream);

    const int TB = 256;
    const int egrid4 = (E_TOT + TB * 4 - 1) / (TB * 4);
    const int ggrid = (N_NODES + 63) / 64;
    const int pgrid = (N_NODES + POOL_NODES - 1) / POOL_NODES;

    // CSR build (shared by both layers)
    hist_kernel<<<egrid4, TB, 0, stream>>>(ei, deg);
    scan_partial_kernel<<<N_TILES, TB, 0, stream>>>(deg, tile_sums);
    scan_tilesums_kernel<<<1, 64, 0, stream>>>(tile_sums, tile_off);
    scan_apply_kernel<<<N_TILES, TB, 0, stream>>>(deg, tile_off, row_start);
    scatter_kernel<<<egrid4, TB, 0, stream>>>(ei, row_start, cursor, csr_src);

    // ---- layer 1 ----
    gemm_att_kernel<F_IN><<<ggrid, TB, 0, stream>>>(x, W1, as1, ad1, A, es, ed);
    gat_aggregate_kernel<<<N_NODES / 4, TB, 0, stream>>>(A, es, ed, row_start, csr_src, b1, B);
    bn_stats_kernel<<<512, TB, 0, stream>>>(B, stats1);
    bn_apply_kernel<<<2048, TB, 0, stream>>>(B, stats1, bn1g, bn1b);

    // ---- layer 2 ----
    gemm_att_kernel<HIDDEN><<<ggrid, TB, 0, stream>>>(B, W2, as2, ad2, A, es, ed);
    gat_aggregate_kernel<<<N_NODES / 4, TB, 0, stream>>>(A, es, ed, row_start, csr_src, b2, B);
    bn_stats_kernel<<<512, TB, 0, stream>>>(B, stats2);
    bn_apply_pool_kernel<<<pgrid, TB, 0, stream>>>(B, stats2, bn2g, bn2b, batch, psum, pcnt);

    // ---- final linear ----
    final_kernel<<<(N_GRAPHS * OUT_DIM) / TB, TB, 0, stream>>>(psum, pcnt, Wlin, blin, out);
}

// Round 14
// 455.652 us; speedup vs baseline: 1.0118x; 1.0118x over previous
//
#include <hip/hip_runtime.h>
#include <hip/hip_bf16.h>
#include <hip/hip_fp16.h>
#include <math.h>

#define N_NODES 50000
#define N_EDGES 800000
#define E_TOT   (N_EDGES + N_NODES)
#define F_IN    64
#define HIDDEN  128
#define HEADS   4
#define OUT_DIM 256
#define N_GRAPHS 1024
#define BN_EPS  1e-5f
#define SLOPE   0.2f

#define SCAN_TILE 2048
#define N_TILES   ((N_NODES + SCAN_TILE - 1) / SCAN_TILE)   // 25
#define POOL_NODES 128

// ---------------- CSR build ----------------

// 4 edges/thread: 4 independent atomic chains in flight
__global__ void hist_kernel(const int* __restrict__ ei, int* __restrict__ deg) {
    int base = blockIdx.x * blockDim.x * 4 + threadIdx.x;
    #pragma unroll
    for (int u = 0; u < 4; ++u) {
        int i = base + u * 256;
        if (i < E_TOT) {
            int d = (i < N_EDGES) ? ei[N_EDGES + i] : (i - N_EDGES);
            atomicAdd(&deg[d], 1);
        }
    }
}

__global__ void scan_partial_kernel(const int* __restrict__ deg, int* __restrict__ tile_sums) {
    __shared__ int wsum[4];
    int tile = blockIdx.x;
    int tid = threadIdx.x;
    int base = tile * SCAN_TILE + tid * 8;
    int s = 0;
    #pragma unroll
    for (int k = 0; k < 8; ++k) {
        int i = base + k;
        if (i < N_NODES) s += deg[i];
    }
    int lane = tid & 63;
    for (int off = 1; off < 64; off <<= 1) s += __shfl_xor(s, off, 64);
    if (lane == 0) wsum[tid >> 6] = s;
    __syncthreads();
    if (tid == 0) tile_sums[tile] = wsum[0] + wsum[1] + wsum[2] + wsum[3];
}

__global__ void scan_tilesums_kernel(const int* __restrict__ tile_sums, int* __restrict__ tile_off) {
    if (threadIdx.x == 0) {
        int acc = 0;
        for (int t = 0; t < N_TILES; ++t) { tile_off[t] = acc; acc += tile_sums[t]; }
    }
}

__global__ void scan_apply_kernel(const int* __restrict__ deg, const int* __restrict__ tile_off,
                                  int* __restrict__ row_start) {
    __shared__ int wsum[4];
    int tile = blockIdx.x;
    int tid = threadIdx.x;
    int lane = tid & 63;
    int wid = tid >> 6;
    int base = tile * SCAN_TILE + tid * 8;
    int v[8];
    int tsum = 0;
    #pragma unroll
    for (int k = 0; k < 8; ++k) {
        int i = base + k;
        v[k] = (i < N_NODES) ? deg[i] : 0;
        tsum += v[k];
    }
    int sc = tsum;
    for (int off = 1; off < 64; off <<= 1) {
        int t = __shfl_up(sc, off, 64);
        if (lane >= off) sc += t;
    }
    if (lane == 63) wsum[wid] = sc;
    __syncthreads();
    int woff = 0;
    for (int w = 0; w < 4; ++w) woff += (w < wid) ? wsum[w] : 0;
    __syncthreads();
    int toff = tile_off[tile] + woff + (sc - tsum);
    #pragma unroll
    for (int k = 0; k < 8; ++k) {
        int i = base + k;
        if (i < N_NODES) row_start[i] = toff;
        toff += v[k];
    }
    if (tile == 0 && tid == 0) row_start[N_NODES] = E_TOT;
}

// 4 edges/thread; csr entries stored as uint16 (node ids < 65536) -> half the
// scattered-store bytes -> roughly half the amplified HBM write traffic.
__global__ void scatter_kernel(const int* __restrict__ ei, const int* __restrict__ row_start,
                               int* __restrict__ cursor, unsigned short* __restrict__ csr_src) {
    int base = blockIdx.x * blockDim.x * 4 + threadIdx.x;
    int s[4], d[4];
    bool ok[4];
    #pragma unroll
    for (int u = 0; u < 4; ++u) {
        int i = base + u * 256;
        ok[u] = i < E_TOT;
        if (ok[u]) {
            if (i < N_EDGES) { s[u] = ei[i]; d[u] = ei[N_EDGES + i]; }
            else             { s[u] = i - N_EDGES; d[u] = s[u]; }
        }
    }
    int pos[4];
    #pragma unroll
    for (int u = 0; u < 4; ++u)
        if (ok[u]) pos[u] = atomicAdd(&cursor[d[u]], 1);
    #pragma unroll
    for (int u = 0; u < 4; ++u)
        if (ok[u]) csr_src[row_start[d[u]] + pos[u]] = (unsigned short)s[u];
}

// ---------------- LDS-staged GEMM + attention scores (H stored fp16) ----------------
template<int FIN>
__global__ __launch_bounds__(256) void gemm_att_kernel(
        const float* __restrict__ X, const float* __restrict__ W,
        const float* __restrict__ a_src, const float* __restrict__ a_dst,
        __half* __restrict__ H, float* __restrict__ es, float* __restrict__ ed) {
    __shared__ float Wl[FIN * HIDDEN];
    int tid = threadIdx.x;
    for (int i = tid * 4; i < FIN * HIDDEN; i += 256 * 4) {
        *reinterpret_cast<float4*>(&Wl[i]) = *reinterpret_cast<const float4*>(&W[i]);
    }
    __syncthreads();

    int cg = tid & 15;
    int np = tid >> 4;
    int nb = blockIdx.x * 64 + np * 4;
    int j0 = cg * 8;

    bool ok[4];
    const float* xp[4];
    #pragma unroll
    for (int t = 0; t < 4; ++t) {
        ok[t] = (nb + t) < N_NODES;
        xp[t] = X + (size_t)(ok[t] ? nb + t : 0) * FIN;
    }
    float acc[4][8];
    #pragma unroll
    for (int t = 0; t < 4; ++t)
        #pragma unroll
        for (int c = 0; c < 8; ++c) acc[t][c] = 0.f;

    for (int k = 0; k < FIN; k += 4) {
        float4 xa[4];
        #pragma unroll
        for (int t = 0; t < 4; ++t) xa[t] = *reinterpret_cast<const float4*>(xp[t] + k);
        #pragma unroll
        for (int kk = 0; kk < 4; ++kk) {
            const float4 wA = *reinterpret_cast<const float4*>(&Wl[(k + kk) * HIDDEN + j0]);
            const float4 wB = *reinterpret_cast<const float4*>(&Wl[(k + kk) * HIDDEN + j0 + 4]);
            #pragma unroll
            for (int t = 0; t < 4; ++t) {
                float xv = (kk == 0) ? xa[t].x : (kk == 1) ? xa[t].y : (kk == 2) ? xa[t].z : xa[t].w;
                acc[t][0] += xv * wA.x; acc[t][1] += xv * wA.y;
                acc[t][2] += xv * wA.z; acc[t][3] += xv * wA.w;
                acc[t][4] += xv * wB.x; acc[t][5] += xv * wB.y;
                acc[t][6] += xv * wB.z; acc[t][7] += xv * wB.w;
            }
        }
    }

    #pragma unroll
    for (int t = 0; t < 4; ++t) {
        int n = nb + t;
        if (ok[t]) {
            union { __half2 h2[4]; float4 f4; } pk;
            pk.h2[0] = __floats2half2_rn(acc[t][0], acc[t][1]);
            pk.h2[1] = __floats2half2_rn(acc[t][2], acc[t][3]);
            pk.h2[2] = __floats2half2_rn(acc[t][4], acc[t][5]);
            pk.h2[3] = __floats2half2_rn(acc[t][6], acc[t][7]);
            *reinterpret_cast<float4*>(H + (size_t)n * HIDDEN + j0) = pk.f4;
        }
        float vs = 0.f, vd = 0.f;
        #pragma unroll
        for (int c = 0; c < 8; ++c) {
            vs += acc[t][c] * a_src[j0 + c];
            vd += acc[t][c] * a_dst[j0 + c];
        }
        vs += __shfl_xor(vs, 1, 64); vs += __shfl_xor(vs, 2, 64);
        vd += __shfl_xor(vd, 1, 64); vd += __shfl_xor(vd, 2, 64);
        if ((cg & 3) == 0 && ok[t]) {
            int h = cg >> 2;
            es[n * HEADS + h] = vs;
            ed[n * HEADS + h] = vd;
        }
    }
}

// ---------------- per-node GAT aggregation (1 wave / node, fp16 gather, 4x unroll) ----------------
__global__ void gat_aggregate_kernel(const __half* __restrict__ H, const float* __restrict__ es,
                                     const float* __restrict__ ed, const int* __restrict__ row_start,
                                     const unsigned short* __restrict__ csr_src,
                                     const float* __restrict__ bias,
                                     float* __restrict__ out) {
    int lane = threadIdx.x & 63;
    int n = blockIdx.x * 4 + (threadIdx.x >> 6);
    if (n >= N_NODES) return;
    int hid = lane >> 4;
    float edn = ed[n * HEADS + hid];
    int k0 = row_start[n], k1 = row_start[n + 1];
    const __half2* Hp = reinterpret_cast<const __half2*>(H);
    float dsum = 0.f, accx = 0.f, accy = 0.f;
    int k = k0;
    for (; k + 3 < k1; k += 4) {
        int s0 = csr_src[k];
        int s1 = csr_src[k + 1];
        int s2 = csr_src[k + 2];
        int s3 = csr_src[k + 3];
        float e0 = es[s0 * HEADS + hid];
        float e1 = es[s1 * HEADS + hid];
        float e2 = es[s2 * HEADS + hid];
        float e3 = es[s3 * HEADS + hid];
        __half2 h0 = Hp[(size_t)s0 * (HIDDEN / 2) + lane];
        __half2 h1 = Hp[(size_t)s1 * (HIDDEN / 2) + lane];
        __half2 h2 = Hp[(size_t)s2 * (HIDDEN / 2) + lane];
        __half2 h3 = Hp[(size_t)s3 * (HIDDEN / 2) + lane];
        e0 += edn; e1 += edn; e2 += edn; e3 += edn;
        // leaky-relu as single max (SLOPE < 1)
        e0 = fmaxf(e0, SLOPE * e0);
        e1 = fmaxf(e1, SLOPE * e1);
        e2 = fmaxf(e2, SLOPE * e2);
        e3 = fmaxf(e3, SLOPE * e3);
        float ex0 = __expf(e0);
        float ex1 = __expf(e1);
        float ex2 = __expf(e2);
        float ex3 = __expf(e3);
        float2 f0 = __half22float2(h0);
        float2 f1 = __half22float2(h1);
        float2 f2 = __half22float2(h2);
        float2 f3 = __half22float2(h3);
        dsum += (ex0 + ex1) + (ex2 + ex3);
        accx += ex0 * f0.x + ex1 * f1.x + ex2 * f2.x + ex3 * f3.x;
        accy += ex0 * f0.y + ex1 * f1.y + ex2 * f2.y + ex3 * f3.y;
    }
    for (; k < k1; ++k) {
        int s0 = csr_src[k];
        float e0 = es[s0 * HEADS + hid] + edn;
        __half2 h0 = Hp[(size_t)s0 * (HIDDEN / 2) + lane];
        e0 = fmaxf(e0, SLOPE * e0);
        float ex0 = __expf(e0);
        float2 f0 = __half22float2(h0);
        dsum += ex0;
        accx += ex0 * f0.x;
        accy += ex0 * f0.y;
    }
    float inv = 1.f / (dsum + 1e-16f);
    int j = 2 * lane;
    out[(size_t)n * HIDDEN + j]     = accx * inv + bias[j];
    out[(size_t)n * HIDDEN + j + 1] = accy * inv + bias[j + 1];
}

// ---------------- BatchNorm (2-pass) + ELU ----------------
__global__ void bn_stats_kernel(const float* __restrict__ X, float* __restrict__ stats) {
    int c = threadIdx.x & 127;
    int r0 = blockIdx.x * 2 + (threadIdx.x >> 7);
    float s = 0.f, s2 = 0.f;
    for (int n = r0; n < N_NODES; n += gridDim.x * 2) {
        float v = X[(size_t)n * HIDDEN + c];
        s += v;
        s2 += v * v;
    }
    atomicAdd(&stats[c], s);
    atomicAdd(&stats[HIDDEN + c], s2);
}

__global__ void bn_apply_kernel(float* __restrict__ X, const float* __restrict__ stats,
                                const float* __restrict__ g, const float* __restrict__ b) {
    const float invN = 1.f / (float)N_NODES;
    int i = blockIdx.x * blockDim.x + threadIdx.x;
    const int total = N_NODES * HIDDEN;
    for (; i < total; i += gridDim.x * blockDim.x) {
        int c = i & 127;
        float mu = stats[c] * invN;
        float var = stats[HIDDEN + c] * invN - mu * mu;
        float v = (X[i] - mu) * rsqrtf(var + BN_EPS) * g[c] + b[c];
        X[i] = (v > 0.f) ? v : expm1f(v);
    }
}

// layer-2: BN+ELU fused into pooling, exploiting SORTED batch
__global__ __launch_bounds__(256) void bn_apply_pool_kernel(
        const float* __restrict__ X, const float* __restrict__ stats,
        const float* __restrict__ g, const float* __restrict__ b,
        const int* __restrict__ batch,
        float* __restrict__ psum, float* __restrict__ pcnt) {
    const float invN = 1.f / (float)N_NODES;
    int c = threadIdx.x & 127;
    int h = threadIdx.x >> 7;
    int n0 = blockIdx.x * POOL_NODES + h * (POOL_NODES / 2);
    int n1 = n0 + POOL_NODES / 2;
    if (n1 > N_NODES) n1 = N_NODES;
    if (n0 >= n1) return;
    float mu = stats[c] * invN;
    float var = stats[HIDDEN + c] * invN - mu * mu;
    float sc = rsqrtf(var + BN_EPS) * g[c];
    float sh = b[c] - mu * sc;
    int cur = batch[n0];
    float racc = 0.f, rcnt = 0.f;
    for (int n = n0; n < n1; ++n) {
        int gi = batch[n];
        if (gi != cur) {
            atomicAdd(&psum[cur * HIDDEN + c], racc);
            if (c == 0) atomicAdd(&pcnt[cur], rcnt);
            racc = 0.f; rcnt = 0.f; cur = gi;
        }
        float v = X[(size_t)n * HIDDEN + c] * sc + sh;
        v = (v > 0.f) ? v : expm1f(v);
        racc += v;
        rcnt += 1.f;
    }
    atomicAdd(&psum[cur * HIDDEN + c], racc);
    if (c == 0) atomicAdd(&pcnt[cur], rcnt);
}

// ---------------- final linear ----------------
__global__ void final_kernel(const float* __restrict__ psum, const float* __restrict__ pcnt,
                             const float* __restrict__ Wlin, const float* __restrict__ blin,
                             float* __restrict__ out) {
    int idx = blockIdx.x * blockDim.x + threadIdx.x;
    int g = idx >> 8, o = idx & 255;
    float invc = 1.f / fmaxf(pcnt[g], 1.f);
    float acc = blin[o];
    const float* pr = psum + g * HIDDEN;
    for (int j = 0; j < HIDDEN; ++j)
        acc += pr[j] * invc * Wlin[j * OUT_DIM + o];
    out[idx] = acc;
}

// ---------------- launch ----------------

extern "C" void kernel_launch(void* const* d_in, const int* in_sizes, int n_in,
                              void* d_out, int out_size, void* d_ws, size_t ws_size,
                              hipStream_t stream) {
    const float* x    = (const float*)d_in[0];
    const int*   ei   = (const int*)d_in[1];
    const int*   batch= (const int*)d_in[2];
    const float* W1   = (const float*)d_in[3];
    const float* as1  = (const float*)d_in[4];
    const float* ad1  = (const float*)d_in[5];
    const float* b1   = (const float*)d_in[6];
    const float* W2   = (const float*)d_in[7];
    const float* as2  = (const float*)d_in[8];
    const float* ad2  = (const float*)d_in[9];
    const float* b2   = (const float*)d_in[10];
    const float* bn1g = (const float*)d_in[11];
    const float* bn1b = (const float*)d_in[12];
    const float* bn2g = (const float*)d_in[13];
    const float* bn2b = (const float*)d_in[14];
    const float* Wlin = (const float*)d_in[15];
    const float* blin = (const float*)d_in[16];
    float* out = (float*)d_out;

    char* ws = (char*)d_ws;
    const size_t SZ_H = (size_t)N_NODES * HIDDEN * 4;
    __half* A       = (__half*)(ws);                      // fp16 H
    float* B        = (float*)(ws + SZ_H);
    size_t off = 2 * SZ_H;
    float* es       = (float*)(ws + off); off += (size_t)N_NODES * HEADS * 4;
    float* ed       = (float*)(ws + off); off += (size_t)N_NODES * HEADS * 4;
    int*   row_start= (int*)(ws + off);   off += ((size_t)(N_NODES + 1) * 4 + 511) & ~511ull;
    unsigned short* csr_src = (unsigned short*)(ws + off);
    off += ((size_t)E_TOT * 2 + 511) & ~511ull;
    int*   tile_sums= (int*)(ws + off);   off += ((size_t)N_TILES * 4 + 511) & ~511ull;
    int*   tile_off = (int*)(ws + off);   off += ((size_t)N_TILES * 4 + 511) & ~511ull;
    size_t zoff = off;
    int*   deg      = (int*)(ws + off);   off += (size_t)N_NODES * 4;
    int*   cursor   = (int*)(ws + off);   off += (size_t)N_NODES * 4;
    float* stats1   = (float*)(ws + off); off += 2 * HIDDEN * 4;
    float* stats2   = (float*)(ws + off); off += 2 * HIDDEN * 4;
    float* psum     = (float*)(ws + off); off += (size_t)N_GRAPHS * HIDDEN * 4;
    float* pcnt     = (float*)(ws + off); off += (size_t)N_GRAPHS * 4;
    size_t zbytes = off - zoff;
    (void)ws_size; (void)n_in; (void)in_sizes; (void)out_size;

    hipMemsetAsync(ws + zoff, 0, zbytes, stream);

    const int TB = 256;
    const int egrid4 = (E_TOT + TB * 4 - 1) / (TB * 4);
    const int ggrid = (N_NODES + 63) / 64;
    const int pgrid = (N_NODES + POOL_NODES - 1) / POOL_NODES;

    // CSR build (shared by both layers)
    hist_kernel<<<egrid4, TB, 0, stream>>>(ei, deg);
    scan_partial_kernel<<<N_TILES, TB, 0, stream>>>(deg, tile_sums);
    scan_tilesums_kernel<<<1, 64, 0, stream>>>(tile_sums, tile_off);
    scan_apply_kernel<<<N_TILES, TB, 0, stream>>>(deg, tile_off, row_start);
    scatter_kernel<<<egrid4, TB, 0, stream>>>(ei, row_start, cursor, csr_src);

    // ---- layer 1 ----
    gemm_att_kernel<F_IN><<<ggrid, TB, 0, stream>>>(x, W1, as1, ad1, A, es, ed);
    gat_aggregate_kernel<<<N_NODES / 4, TB, 0, stream>>>(A, es, ed, row_start, csr_src, b1, B);
    bn_stats_kernel<<<512, TB, 0, stream>>>(B, stats1);
    bn_apply_kernel<<<2048, TB, 0, stream>>>(B, stats1, bn1g, bn1b);

    // ---- layer 2 ----
    gemm_att_kernel<HIDDEN><<<ggrid, TB, 0, stream>>>(B, W2, as2, ad2, A, es, ed);
    gat_aggregate_kernel<<<N_NODES / 4, TB, 0, stream>>>(A, es, ed, row_start, csr_src, b2, B);
    bn_stats_kernel<<<512, TB, 0, stream>>>(B, stats2);
    bn_apply_pool_kernel<<<pgrid, TB, 0, stream>>>(B, stats2, bn2g, bn2b, batch, psum, pcnt);

    // ---- final linear ----
    final_kernel<<<(N_GRAPHS * OUT_DIM) / TB, TB, 0, stream>>>(psum, pcnt, Wlin, blin, out);
}

// Round 15
// 450.611 us; speedup vs baseline: 1.0231x; 1.0112x over previous
//
#include <hip/hip_runtime.h>
#include <hip/hip_bf16.h>
#include <hip/hip_fp16.h>
#include <math.h>

#define N_NODES 50000
#define N_EDGES 800000
#define E_TOT   (N_EDGES + N_NODES)
#define F_IN    64
#define HIDDEN  128
#define HEADS   4
#define OUT_DIM 256
#define N_GRAPHS 1024
#define BN_EPS  1e-5f
#define SLOPE   0.2f

#define SCAN_TILE 2048
#define N_TILES   ((N_NODES + SCAN_TILE - 1) / SCAN_TILE)   // 25
#define POOL_NODES 128
#define SCATTER_BLOCKS ((E_TOT + 1023) / 1024)              // 831 (4 edges/thread)
#define GEMM_BLOCKS    ((N_NODES + 63) / 64)                // 782

// ---------------- CSR build ----------------

// 4 edges/thread: 4 independent atomic chains in flight
__global__ void hist_kernel(const int* __restrict__ ei, int* __restrict__ deg) {
    int base = blockIdx.x * blockDim.x * 4 + threadIdx.x;
    #pragma unroll
    for (int u = 0; u < 4; ++u) {
        int i = base + u * 256;
        if (i < E_TOT) {
            int d = (i < N_EDGES) ? ei[N_EDGES + i] : (i - N_EDGES);
            atomicAdd(&deg[d], 1);
        }
    }
}

__global__ void scan_partial_kernel(const int* __restrict__ deg, int* __restrict__ tile_sums) {
    __shared__ int wsum[4];
    int tile = blockIdx.x;
    int tid = threadIdx.x;
    int base = tile * SCAN_TILE + tid * 8;
    int s = 0;
    #pragma unroll
    for (int k = 0; k < 8; ++k) {
        int i = base + k;
        if (i < N_NODES) s += deg[i];
    }
    int lane = tid & 63;
    for (int off = 1; off < 64; off <<= 1) s += __shfl_xor(s, off, 64);
    if (lane == 0) wsum[tid >> 6] = s;
    __syncthreads();
    if (tid == 0) tile_sums[tile] = wsum[0] + wsum[1] + wsum[2] + wsum[3];
}

__global__ void scan_tilesums_kernel(const int* __restrict__ tile_sums, int* __restrict__ tile_off) {
    if (threadIdx.x == 0) {
        int acc = 0;
        for (int t = 0; t < N_TILES; ++t) { tile_off[t] = acc; acc += tile_sums[t]; }
    }
}

__global__ void scan_apply_kernel(const int* __restrict__ deg, const int* __restrict__ tile_off,
                                  int* __restrict__ row_start) {
    __shared__ int wsum[4];
    int tile = blockIdx.x;
    int tid = threadIdx.x;
    int lane = tid & 63;
    int wid = tid >> 6;
    int base = tile * SCAN_TILE + tid * 8;
    int v[8];
    int tsum = 0;
    #pragma unroll
    for (int k = 0; k < 8; ++k) {
        int i = base + k;
        v[k] = (i < N_NODES) ? deg[i] : 0;
        tsum += v[k];
    }
    int sc = tsum;
    for (int off = 1; off < 64; off <<= 1) {
        int t = __shfl_up(sc, off, 64);
        if (lane >= off) sc += t;
    }
    if (lane == 63) wsum[wid] = sc;
    __syncthreads();
    int woff = 0;
    for (int w = 0; w < 4; ++w) woff += (w < wid) ? wsum[w] : 0;
    __syncthreads();
    int toff = tile_off[tile] + woff + (sc - tsum);
    #pragma unroll
    for (int k = 0; k < 8; ++k) {
        int i = base + k;
        if (i < N_NODES) row_start[i] = toff;
        toff += v[k];
    }
    if (tile == 0 && tid == 0) row_start[N_NODES] = E_TOT;
}

// ---------------- device bodies (for fusion) ----------------

__device__ __forceinline__ void scatter_body(const int* __restrict__ ei,
                                             const int* __restrict__ row_start,
                                             int* __restrict__ cursor,
                                             unsigned short* __restrict__ csr_src,
                                             int bid) {
    int base = bid * 1024 + threadIdx.x;
    int s[4], d[4];
    bool ok[4];
    #pragma unroll
    for (int u = 0; u < 4; ++u) {
        int i = base + u * 256;
        ok[u] = i < E_TOT;
        if (ok[u]) {
            if (i < N_EDGES) { s[u] = ei[i]; d[u] = ei[N_EDGES + i]; }
            else             { s[u] = i - N_EDGES; d[u] = s[u]; }
        }
    }
    int pos[4];
    #pragma unroll
    for (int u = 0; u < 4; ++u)
        if (ok[u]) pos[u] = atomicAdd(&cursor[d[u]], 1);
    #pragma unroll
    for (int u = 0; u < 4; ++u)
        if (ok[u]) csr_src[row_start[d[u]] + pos[u]] = (unsigned short)s[u];
}

template<int FIN>
__device__ __forceinline__ void gemm_att_body(
        const float* __restrict__ X, const float* __restrict__ W,
        const float* __restrict__ a_src, const float* __restrict__ a_dst,
        __half* __restrict__ H, float* __restrict__ es, float* __restrict__ ed,
        int bid, float* Wl) {
    int tid = threadIdx.x;
    for (int i = tid * 4; i < FIN * HIDDEN; i += 256 * 4) {
        *reinterpret_cast<float4*>(&Wl[i]) = *reinterpret_cast<const float4*>(&W[i]);
    }
    __syncthreads();

    int cg = tid & 15;
    int np = tid >> 4;
    int nb = bid * 64 + np * 4;
    int j0 = cg * 8;

    bool ok[4];
    const float* xp[4];
    #pragma unroll
    for (int t = 0; t < 4; ++t) {
        ok[t] = (nb + t) < N_NODES;
        xp[t] = X + (size_t)(ok[t] ? nb + t : 0) * FIN;
    }
    float acc[4][8];
    #pragma unroll
    for (int t = 0; t < 4; ++t)
        #pragma unroll
        for (int c = 0; c < 8; ++c) acc[t][c] = 0.f;

    for (int k = 0; k < FIN; k += 4) {
        float4 xa[4];
        #pragma unroll
        for (int t = 0; t < 4; ++t) xa[t] = *reinterpret_cast<const float4*>(xp[t] + k);
        #pragma unroll
        for (int kk = 0; kk < 4; ++kk) {
            const float4 wA = *reinterpret_cast<const float4*>(&Wl[(k + kk) * HIDDEN + j0]);
            const float4 wB = *reinterpret_cast<const float4*>(&Wl[(k + kk) * HIDDEN + j0 + 4]);
            #pragma unroll
            for (int t = 0; t < 4; ++t) {
                float xv = (kk == 0) ? xa[t].x : (kk == 1) ? xa[t].y : (kk == 2) ? xa[t].z : xa[t].w;
                acc[t][0] += xv * wA.x; acc[t][1] += xv * wA.y;
                acc[t][2] += xv * wA.z; acc[t][3] += xv * wA.w;
                acc[t][4] += xv * wB.x; acc[t][5] += xv * wB.y;
                acc[t][6] += xv * wB.z; acc[t][7] += xv * wB.w;
            }
        }
    }

    #pragma unroll
    for (int t = 0; t < 4; ++t) {
        int n = nb + t;
        if (ok[t]) {
            union { __half2 h2[4]; float4 f4; } pk;
            pk.h2[0] = __floats2half2_rn(acc[t][0], acc[t][1]);
            pk.h2[1] = __floats2half2_rn(acc[t][2], acc[t][3]);
            pk.h2[2] = __floats2half2_rn(acc[t][4], acc[t][5]);
            pk.h2[3] = __floats2half2_rn(acc[t][6], acc[t][7]);
            *reinterpret_cast<float4*>(H + (size_t)n * HIDDEN + j0) = pk.f4;
        }
        float vs = 0.f, vd = 0.f;
        #pragma unroll
        for (int c = 0; c < 8; ++c) {
            vs += acc[t][c] * a_src[j0 + c];
            vd += acc[t][c] * a_dst[j0 + c];
        }
        vs += __shfl_xor(vs, 1, 64); vs += __shfl_xor(vs, 2, 64);
        vd += __shfl_xor(vd, 1, 64); vd += __shfl_xor(vd, 2, 64);
        if ((cg & 3) == 0 && ok[t]) {
            int h = cg >> 2;
            es[n * HEADS + h] = vs;
            ed[n * HEADS + h] = vd;
        }
    }
}

// fused: scatter blocks backfilled with layer-1 GEMM blocks (independent work)
__global__ __launch_bounds__(256) void scatter_gemm1_kernel(
        const int* __restrict__ ei, const int* __restrict__ row_start,
        int* __restrict__ cursor, unsigned short* __restrict__ csr_src,
        const float* __restrict__ X, const float* __restrict__ W,
        const float* __restrict__ a_src, const float* __restrict__ a_dst,
        __half* __restrict__ H, float* __restrict__ es, float* __restrict__ ed) {
    __shared__ float Wl[F_IN * HIDDEN];
    int bid = blockIdx.x;
    if (bid < SCATTER_BLOCKS) {
        scatter_body(ei, row_start, cursor, csr_src, bid);
    } else {
        gemm_att_body<F_IN>(X, W, a_src, a_dst, H, es, ed, bid - SCATTER_BLOCKS, Wl);
    }
}

// standalone layer-2 GEMM
__global__ __launch_bounds__(256) void gemm_att2_kernel(
        const float* __restrict__ X, const float* __restrict__ W,
        const float* __restrict__ a_src, const float* __restrict__ a_dst,
        __half* __restrict__ H, float* __restrict__ es, float* __restrict__ ed) {
    __shared__ float Wl[HIDDEN * HIDDEN];
    gemm_att_body<HIDDEN>(X, W, a_src, a_dst, H, es, ed, blockIdx.x, Wl);
}

// ---------------- per-node GAT aggregation (1 wave / node, fp16 gather, 4x unroll) ----------------
__global__ void gat_aggregate_kernel(const __half* __restrict__ H, const float* __restrict__ es,
                                     const float* __restrict__ ed, const int* __restrict__ row_start,
                                     const unsigned short* __restrict__ csr_src,
                                     const float* __restrict__ bias,
                                     float* __restrict__ out) {
    int lane = threadIdx.x & 63;
    int n = blockIdx.x * 4 + (threadIdx.x >> 6);
    if (n >= N_NODES) return;
    int hid = lane >> 4;
    float edn = ed[n * HEADS + hid];
    int k0 = row_start[n], k1 = row_start[n + 1];
    const __half2* Hp = reinterpret_cast<const __half2*>(H);
    float dsum = 0.f, accx = 0.f, accy = 0.f;
    int k = k0;
    for (; k + 3 < k1; k += 4) {
        int s0 = csr_src[k];
        int s1 = csr_src[k + 1];
        int s2 = csr_src[k + 2];
        int s3 = csr_src[k + 3];
        float e0 = es[s0 * HEADS + hid];
        float e1 = es[s1 * HEADS + hid];
        float e2 = es[s2 * HEADS + hid];
        float e3 = es[s3 * HEADS + hid];
        __half2 h0 = Hp[(size_t)s0 * (HIDDEN / 2) + lane];
        __half2 h1 = Hp[(size_t)s1 * (HIDDEN / 2) + lane];
        __half2 h2 = Hp[(size_t)s2 * (HIDDEN / 2) + lane];
        __half2 h3 = Hp[(size_t)s3 * (HIDDEN / 2) + lane];
        e0 += edn; e1 += edn; e2 += edn; e3 += edn;
        e0 = fmaxf(e0, SLOPE * e0);
        e1 = fmaxf(e1, SLOPE * e1);
        e2 = fmaxf(e2, SLOPE * e2);
        e3 = fmaxf(e3, SLOPE * e3);
        float ex0 = __expf(e0);
        float ex1 = __expf(e1);
        float ex2 = __expf(e2);
        float ex3 = __expf(e3);
        float2 f0 = __half22float2(h0);
        float2 f1 = __half22float2(h1);
        float2 f2 = __half22float2(h2);
        float2 f3 = __half22float2(h3);
        dsum += (ex0 + ex1) + (ex2 + ex3);
        accx += ex0 * f0.x + ex1 * f1.x + ex2 * f2.x + ex3 * f3.x;
        accy += ex0 * f0.y + ex1 * f1.y + ex2 * f2.y + ex3 * f3.y;
    }
    for (; k < k1; ++k) {
        int s0 = csr_src[k];
        float e0 = es[s0 * HEADS + hid] + edn;
        __half2 h0 = Hp[(size_t)s0 * (HIDDEN / 2) + lane];
        e0 = fmaxf(e0, SLOPE * e0);
        float ex0 = __expf(e0);
        float2 f0 = __half22float2(h0);
        dsum += ex0;
        accx += ex0 * f0.x;
        accy += ex0 * f0.y;
    }
    float inv = 1.f / (dsum + 1e-16f);
    int j = 2 * lane;
    out[(size_t)n * HIDDEN + j]     = accx * inv + bias[j];
    out[(size_t)n * HIDDEN + j + 1] = accy * inv + bias[j + 1];
}

// ---------------- BatchNorm (2-pass) + ELU ----------------
__global__ void bn_stats_kernel(const float* __restrict__ X, float* __restrict__ stats) {
    int c = threadIdx.x & 127;
    int r0 = blockIdx.x * 2 + (threadIdx.x >> 7);
    float s = 0.f, s2 = 0.f;
    for (int n = r0; n < N_NODES; n += gridDim.x * 2) {
        float v = X[(size_t)n * HIDDEN + c];
        s += v;
        s2 += v * v;
    }
    atomicAdd(&stats[c], s);
    atomicAdd(&stats[HIDDEN + c], s2);
}

__global__ void bn_apply_kernel(float* __restrict__ X, const float* __restrict__ stats,
                                const float* __restrict__ g, const float* __restrict__ b) {
    const float invN = 1.f / (float)N_NODES;
    int i = blockIdx.x * blockDim.x + threadIdx.x;
    const int total = N_NODES * HIDDEN;
    for (; i < total; i += gridDim.x * blockDim.x) {
        int c = i & 127;
        float mu = stats[c] * invN;
        float var = stats[HIDDEN + c] * invN - mu * mu;
        float v = (X[i] - mu) * rsqrtf(var + BN_EPS) * g[c] + b[c];
        X[i] = (v > 0.f) ? v : expm1f(v);
    }
}

// layer-2: BN+ELU fused into pooling, exploiting SORTED batch
__global__ __launch_bounds__(256) void bn_apply_pool_kernel(
        const float* __restrict__ X, const float* __restrict__ stats,
        const float* __restrict__ g, const float* __restrict__ b,
        const int* __restrict__ batch,
        float* __restrict__ psum, float* __restrict__ pcnt) {
    const float invN = 1.f / (float)N_NODES;
    int c = threadIdx.x & 127;
    int h = threadIdx.x >> 7;
    int n0 = blockIdx.x * POOL_NODES + h * (POOL_NODES / 2);
    int n1 = n0 + POOL_NODES / 2;
    if (n1 > N_NODES) n1 = N_NODES;
    if (n0 >= n1) return;
    float mu = stats[c] * invN;
    float var = stats[HIDDEN + c] * invN - mu * mu;
    float sc = rsqrtf(var + BN_EPS) * g[c];
    float sh = b[c] - mu * sc;
    int cur = batch[n0];
    float racc = 0.f, rcnt = 0.f;
    for (int n = n0; n < n1; ++n) {
        int gi = batch[n];
        if (gi != cur) {
            atomicAdd(&psum[cur * HIDDEN + c], racc);
            if (c == 0) atomicAdd(&pcnt[cur], rcnt);
            racc = 0.f; rcnt = 0.f; cur = gi;
        }
        float v = X[(size_t)n * HIDDEN + c] * sc + sh;
        v = (v > 0.f) ? v : expm1f(v);
        racc += v;
        rcnt += 1.f;
    }
    atomicAdd(&psum[cur * HIDDEN + c], racc);
    if (c == 0) atomicAdd(&pcnt[cur], rcnt);
}

// ---------------- final linear ----------------
__global__ void final_kernel(const float* __restrict__ psum, const float* __restrict__ pcnt,
                             const float* __restrict__ Wlin, const float* __restrict__ blin,
                             float* __restrict__ out) {
    int idx = blockIdx.x * blockDim.x + threadIdx.x;
    int g = idx >> 8, o = idx & 255;
    float invc = 1.f / fmaxf(pcnt[g], 1.f);
    float acc = blin[o];
    const float* pr = psum + g * HIDDEN;
    for (int j = 0; j < HIDDEN; ++j)
        acc += pr[j] * invc * Wlin[j * OUT_DIM + o];
    out[idx] = acc;
}

// ---------------- launch ----------------

extern "C" void kernel_launch(void* const* d_in, const int* in_sizes, int n_in,
                              void* d_out, int out_size, void* d_ws, size_t ws_size,
                              hipStream_t stream) {
    const float* x    = (const float*)d_in[0];
    const int*   ei   = (const int*)d_in[1];
    const int*   batch= (const int*)d_in[2];
    const float* W1   = (const float*)d_in[3];
    const float* as1  = (const float*)d_in[4];
    const float* ad1  = (const float*)d_in[5];
    const float* b1   = (const float*)d_in[6];
    const float* W2   = (const float*)d_in[7];
    const float* as2  = (const float*)d_in[8];
    const float* ad2  = (const float*)d_in[9];
    const float* b2   = (const float*)d_in[10];
    const float* bn1g = (const float*)d_in[11];
    const float* bn1b = (const float*)d_in[12];
    const float* bn2g = (const float*)d_in[13];
    const float* bn2b = (const float*)d_in[14];
    const float* Wlin = (const float*)d_in[15];
    const float* blin = (const float*)d_in[16];
    float* out = (float*)d_out;

    char* ws = (char*)d_ws;
    const size_t SZ_H = (size_t)N_NODES * HIDDEN * 4;
    __half* A       = (__half*)(ws);                      // fp16 H
    float* B        = (float*)(ws + SZ_H);
    size_t off = 2 * SZ_H;
    float* es       = (float*)(ws + off); off += (size_t)N_NODES * HEADS * 4;
    float* ed       = (float*)(ws + off); off += (size_t)N_NODES * HEADS * 4;
    int*   row_start= (int*)(ws + off);   off += ((size_t)(N_NODES + 1) * 4 + 511) & ~511ull;
    unsigned short* csr_src = (unsigned short*)(ws + off);
    off += ((size_t)E_TOT * 2 + 511) & ~511ull;
    int*   tile_sums= (int*)(ws + off);   off += ((size_t)N_TILES * 4 + 511) & ~511ull;
    int*   tile_off = (int*)(ws + off);   off += ((size_t)N_TILES * 4 + 511) & ~511ull;
    size_t zoff = off;
    int*   deg      = (int*)(ws + off);   off += (size_t)N_NODES * 4;
    int*   cursor   = (int*)(ws + off);   off += (size_t)N_NODES * 4;
    float* stats1   = (float*)(ws + off); off += 2 * HIDDEN * 4;
    float* stats2   = (float*)(ws + off); off += 2 * HIDDEN * 4;
    float* psum     = (float*)(ws + off); off += (size_t)N_GRAPHS * HIDDEN * 4;
    float* pcnt     = (float*)(ws + off); off += (size_t)N_GRAPHS * 4;
    size_t zbytes = off - zoff;
    (void)ws_size; (void)n_in; (void)in_sizes; (void)out_size;

    hipMemsetAsync(ws + zoff, 0, zbytes, stream);

    const int TB = 256;
    const int egrid4 = SCATTER_BLOCKS;
    const int pgrid = (N_NODES + POOL_NODES - 1) / POOL_NODES;

    // CSR build prefix
    hist_kernel<<<egrid4, TB, 0, stream>>>(ei, deg);
    scan_partial_kernel<<<N_TILES, TB, 0, stream>>>(deg, tile_sums);
    scan_tilesums_kernel<<<1, 64, 0, stream>>>(tile_sums, tile_off);
    scan_apply_kernel<<<N_TILES, TB, 0, stream>>>(deg, tile_off, row_start);

    // ---- fused: scatter (CSR) || layer-1 GEMM (independent) ----
    scatter_gemm1_kernel<<<SCATTER_BLOCKS + GEMM_BLOCKS, TB, 0, stream>>>(
        ei, row_start, cursor, csr_src, x, W1, as1, ad1, A, es, ed);

    // ---- layer 1 rest ----
    gat_aggregate_kernel<<<N_NODES / 4, TB, 0, stream>>>(A, es, ed, row_start, csr_src, b1, B);
    bn_stats_kernel<<<512, TB, 0, stream>>>(B, stats1);
    bn_apply_kernel<<<2048, TB, 0, stream>>>(B, stats1, bn1g, bn1b);

    // ---- layer 2 ----
    gemm_att2_kernel<<<GEMM_BLOCKS, TB, 0, stream>>>(B, W2, as2, ad2, A, es, ed);
    gat_aggregate_kernel<<<N_NODES / 4, TB, 0, stream>>>(A, es, ed, row_start, csr_src, b2, B);
    bn_stats_kernel<<<512, TB, 0, stream>>>(B, stats2);
    bn_apply_pool_kernel<<<pgrid, TB, 0, stream>>>(B, stats2, bn2g, bn2b, batch, psum, pcnt);

    // ---- final linear ----
    final_kernel<<<(N_GRAPHS * OUT_DIM) / TB, TB, 0, stream>>>(psum, pcnt, Wlin, blin, out);
}